// Round 2
// baseline (1143.462 us; speedup 1.0000x reference)
//
#include <hip/hip_runtime.h>

#define B_ 4
#define S_ 2048
#define D_ 1024
#define H_ 16
#define HD_ 64
#define M_ 8192  // B_*S_

typedef __attribute__((ext_vector_type(8))) short          bf16x8;
typedef __attribute__((ext_vector_type(8))) unsigned short u16x8;
typedef __attribute__((ext_vector_type(4))) float          f32x4;

#define MFMA16(a, b, c) __builtin_amdgcn_mfma_f32_16x16x32_bf16((a), (b), (c), 0, 0, 0)

// exp(x*0.125) == exp2(x * 0.125*log2(e)); same constant in both passes so
// l (denominator) and the attn-mean numerator stay consistent.
#define SCL 0.18033688011112042f

__device__ __forceinline__ unsigned short f2b(float f) {  // RTNE fp32->bf16
    unsigned int u = __float_as_uint(f);
    return (unsigned short)((u + 0x7fffu + ((u >> 16) & 1u)) >> 16);
}

// ---------------------------------------------------------------------------
// K0: fp32 -> bf16 cast (x and the three weight matrices)
// ---------------------------------------------------------------------------
__global__ __launch_bounds__(256) void cast_k(const float* __restrict__ src,
                                              unsigned short* __restrict__ dst, int n) {
    int i = (blockIdx.x * 256 + threadIdx.x) * 4;
    if (i >= n) return;
    float4 v = *(const float4*)(src + i);
    ushort4 o;
    o.x = f2b(v.x); o.y = f2b(v.y); o.z = f2b(v.z); o.w = f2b(v.w);
    *(ushort4*)(dst + i) = o;
}

// ---------------------------------------------------------------------------
// K1: QKV projection, bf16 MFMA.  y = x @ W.T + b, W row-major [n][k].
// 128x128 tile, BK=64, 4 waves (2x2), 64x64 per wave = 4x4 frags of 16x16.
// Output bf16 in [B][H][S][HD] layout.
// ---------------------------------------------------------------------------
__global__ __launch_bounds__(256) void qkv_gemm_k(
    const unsigned short* __restrict__ xb,
    const unsigned short* __restrict__ wb0, const unsigned short* __restrict__ wb1,
    const unsigned short* __restrict__ wb2,
    const float* __restrict__ bq, const float* __restrict__ bk, const float* __restrict__ bv,
    unsigned short* __restrict__ Qo, unsigned short* __restrict__ Ko,
    unsigned short* __restrict__ Vo)
{
    __shared__ unsigned short xs[128][72];
    __shared__ unsigned short wsm[128][72];

    const unsigned short* W; const float* bias; unsigned short* out;
    if (blockIdx.z == 0)      { W = wb0; bias = bq; out = Qo; }
    else if (blockIdx.z == 1) { W = wb1; bias = bk; out = Ko; }
    else                      { W = wb2; bias = bv; out = Vo; }

    const int m0 = blockIdx.x * 128, n0 = blockIdx.y * 128;
    const int tid = threadIdx.x, lane = tid & 63, wid = tid >> 6;
    const int wm = (wid >> 1) * 64, wn = (wid & 1) * 64;
    const int srow = tid >> 3;          // 0..31
    const int skc  = (tid & 7) * 8;     // bf16 col 0,8,..,56

    f32x4 acc[4][4] = {};

    for (int k0 = 0; k0 < D_; k0 += 64) {
        u16x8 xa[4], wa[4];
        #pragma unroll
        for (int r = 0; r < 4; ++r) {
            int row = srow + 32 * r;
            xa[r] = *(const u16x8*)&xb[(size_t)(m0 + row) * D_ + k0 + skc];
            wa[r] = *(const u16x8*)&W [(size_t)(n0 + row) * D_ + k0 + skc];
        }
        __syncthreads();
        #pragma unroll
        for (int r = 0; r < 4; ++r) {
            int row = srow + 32 * r;
            *(u16x8*)&xs[row][skc]  = xa[r];
            *(u16x8*)&wsm[row][skc] = wa[r];
        }
        __syncthreads();
        #pragma unroll
        for (int kd = 0; kd < 2; ++kd) {
            const int kc = 32 * kd + 8 * (lane >> 4);
            bf16x8 af[4], bfr[4];
            #pragma unroll
            for (int mf = 0; mf < 4; ++mf)
                af[mf] = *(const bf16x8*)&xs[wm + 16 * mf + (lane & 15)][kc];
            #pragma unroll
            for (int nf = 0; nf < 4; ++nf)
                bfr[nf] = *(const bf16x8*)&wsm[wn + 16 * nf + (lane & 15)][kc];
            #pragma unroll
            for (int mf = 0; mf < 4; ++mf)
                #pragma unroll
                for (int nf = 0; nf < 4; ++nf)
                    acc[mf][nf] = MFMA16(af[mf], bfr[nf], acc[mf][nf]);
        }
    }

    const int col_l = lane & 15, rgrp = lane >> 4;
    #pragma unroll
    for (int nf = 0; nf < 4; ++nf) {
        const int n = n0 + wn + 16 * nf + col_l;
        const float bval = bias[n];
        const int h = n >> 6, d = n & 63;
        #pragma unroll
        for (int mf = 0; mf < 4; ++mf)
            #pragma unroll
            for (int r = 0; r < 4; ++r) {
                int m = m0 + wm + 16 * mf + 4 * rgrp + r;
                int bI = m >> 11, s = m & 2047;
                out[(((size_t)bI * H_ + h) * S_ + s) * HD_ + d] = f2b(acc[mf][nf][r] + bval);
            }
    }
}

// ---------------------------------------------------------------------------
// K2: attention pass 1 (bf16 MFMA). Per block: one (b,h), 128 q-rows.
// Q-frags hoisted to registers; K staged linear; V staged transposed;
// P round-trips through wave-private LDS rows. l = sum exp(s/8) (no max
// subtraction: |s| < ~2).  ctx written unnormalized (f32) + L.
// ---------------------------------------------------------------------------
__global__ __launch_bounds__(256) void attn_ctx_k(
    const unsigned short* __restrict__ Q, const unsigned short* __restrict__ K,
    const unsigned short* __restrict__ V,
    float* __restrict__ L, float* __restrict__ CTX)
{
    __shared__ unsigned short ks[64][72];
    __shared__ unsigned short vt[64][72];   // transposed: vt[d][kpos]
    __shared__ unsigned short ps[128][72];  // wave-private row stripes

    const int q0 = blockIdx.x * 128, h = blockIdx.y, b = blockIdx.z;
    const size_t hoff = ((size_t)(b * H_ + h)) * S_ * HD_;
    const unsigned short* Qh = Q + hoff;
    const unsigned short* Kh = K + hoff;
    const unsigned short* Vh = V + hoff;

    const int tid = threadIdx.x, lane = tid & 63, wid = tid >> 6;
    const int srow = tid >> 3;       // 0..31
    const int skc  = (tid & 7) * 8;

    bf16x8 qf[2][2];
    #pragma unroll
    for (int i = 0; i < 2; ++i)
        #pragma unroll
        for (int kd = 0; kd < 2; ++kd)
            qf[i][kd] = *(const bf16x8*)&Qh[(size_t)(q0 + 32 * wid + 16 * i + (lane & 15)) * HD_
                                            + 32 * kd + 8 * (lane >> 4)];

    f32x4 cacc[2][4] = {};
    float lp[2][4] = {};

    for (int kb = 0; kb < S_; kb += 64) {
        u16x8 ka[2], va[2];
        #pragma unroll
        for (int r = 0; r < 2; ++r) {
            int row = srow + 32 * r;
            ka[r] = *(const u16x8*)&Kh[(size_t)(kb + row) * HD_ + skc];
            va[r] = *(const u16x8*)&Vh[(size_t)(kb + row) * HD_ + skc];
        }
        __syncthreads();   // everyone done reading previous ks/vt
        #pragma unroll
        for (int r = 0; r < 2; ++r) {
            int row = srow + 32 * r;
            *(u16x8*)&ks[row][skc] = ka[r];
            #pragma unroll
            for (int j = 0; j < 8; ++j)
                vt[skc + j][row] = va[r][j];
        }
        __syncthreads();

        // S = Q K^T  (rows q, cols kpos)
        f32x4 sacc[2][4] = {};
        #pragma unroll
        for (int kd = 0; kd < 2; ++kd) {
            const int kc = 32 * kd + 8 * (lane >> 4);
            bf16x8 kf[4];
            #pragma unroll
            for (int n = 0; n < 4; ++n)
                kf[n] = *(const bf16x8*)&ks[16 * n + (lane & 15)][kc];
            #pragma unroll
            for (int i = 0; i < 2; ++i)
                #pragma unroll
                for (int n = 0; n < 4; ++n)
                    sacc[i][n] = MFMA16(qf[i][kd], kf[n], sacc[i][n]);
        }
        // exp, l-partials, stage P (bf16) into wave-private rows
        #pragma unroll
        for (int i = 0; i < 2; ++i)
            #pragma unroll
            for (int n = 0; n < 4; ++n)
                #pragma unroll
                for (int r = 0; r < 4; ++r) {
                    float e = exp2f(sacc[i][n][r] * SCL);
                    lp[i][r] += e;
                    ps[32 * wid + 16 * i + 4 * (lane >> 4) + r][16 * n + (lane & 15)] = f2b(e);
                }
        // ctx += P @ V   (in-wave ds_write->ds_read ordering handled by compiler)
        #pragma unroll
        for (int kk = 0; kk < 2; ++kk) {
            const int kc = 32 * kk + 8 * (lane >> 4);
            bf16x8 pa[2], vf[4];
            #pragma unroll
            for (int i = 0; i < 2; ++i)
                pa[i] = *(const bf16x8*)&ps[32 * wid + 16 * i + (lane & 15)][kc];
            #pragma unroll
            for (int n = 0; n < 4; ++n)
                vf[n] = *(const bf16x8*)&vt[16 * n + (lane & 15)][kc];
            #pragma unroll
            for (int i = 0; i < 2; ++i)
                #pragma unroll
                for (int n = 0; n < 4; ++n)
                    cacc[i][n] = MFMA16(pa[i], vf[n], cacc[i][n]);
        }
    }

    // reduce l across the 16 column-lanes of each row group
    #pragma unroll
    for (int i = 0; i < 2; ++i)
        #pragma unroll
        for (int r = 0; r < 4; ++r) {
            float v = lp[i][r];
            v += __shfl_xor(v, 1); v += __shfl_xor(v, 2);
            v += __shfl_xor(v, 4); v += __shfl_xor(v, 8);
            lp[i][r] = v;
        }
    if ((lane & 15) == 0) {
        #pragma unroll
        for (int i = 0; i < 2; ++i)
            #pragma unroll
            for (int r = 0; r < 4; ++r)
                L[((size_t)(b * H_ + h)) * S_ + q0 + 32 * wid + 16 * i + 4 * (lane >> 4) + r]
                    = lp[i][r];
    }

    // unnormalized ctx (f32) into [B][S][D]
    #pragma unroll
    for (int i = 0; i < 2; ++i)
        #pragma unroll
        for (int n = 0; n < 4; ++n)
            #pragma unroll
            for (int r = 0; r < 4; ++r) {
                int q = q0 + 32 * wid + 16 * i + 4 * (lane >> 4) + r;
                CTX[((size_t)b * S_ + q) * D_ + h * HD_ + 16 * n + (lane & 15)]
                    = cacc[i][n][r];
            }
}

// ---------------------------------------------------------------------------
// K3: attn_mean[b,q,k] = (1/16) sum_h exp(s_h/8)/l_h — second score pass,
// MFMA, no LDS: fragments loaded straight from global (L2/L3-resident).
// Block: 128 q-rows x 64 k-cols, loop over 16 heads.
// ---------------------------------------------------------------------------
__global__ __launch_bounds__(256) void attn_mean_k(
    const unsigned short* __restrict__ Q, const unsigned short* __restrict__ K,
    const float* __restrict__ L, float* __restrict__ attn_out)
{
    const int k0 = blockIdx.x * 64, q0 = blockIdx.y * 128, b = blockIdx.z;
    const int lane = threadIdx.x & 63, wid = threadIdx.x >> 6;
    const int rgrp = lane >> 4, col_l = lane & 15;

    f32x4 macc[2][4] = {};

    for (int h = 0; h < H_; ++h) {
        const size_t hoff = ((size_t)(b * H_ + h)) * S_ * HD_;
        const unsigned short* Qh = Q + hoff;
        const unsigned short* Kh = K + hoff;

        bf16x8 qf[2][2], kf[4][2];
        #pragma unroll
        for (int i = 0; i < 2; ++i)
            #pragma unroll
            for (int kd = 0; kd < 2; ++kd)
                qf[i][kd] = *(const bf16x8*)&Qh[(size_t)(q0 + 32 * wid + 16 * i + col_l) * HD_
                                                + 32 * kd + 8 * rgrp];
        #pragma unroll
        for (int n = 0; n < 4; ++n)
            #pragma unroll
            for (int kd = 0; kd < 2; ++kd)
                kf[n][kd] = *(const bf16x8*)&Kh[(size_t)(k0 + 16 * n + col_l) * HD_
                                                + 32 * kd + 8 * rgrp];

        f32x4 sacc[2][4] = {};
        #pragma unroll
        for (int kd = 0; kd < 2; ++kd)
            #pragma unroll
            for (int i = 0; i < 2; ++i)
                #pragma unroll
                for (int n = 0; n < 4; ++n)
                    sacc[i][n] = MFMA16(qf[i][kd], kf[n][kd], sacc[i][n]);

        float li[2][4];
        #pragma unroll
        for (int i = 0; i < 2; ++i)
            #pragma unroll
            for (int r = 0; r < 4; ++r)
                li[i][r] = 0.0625f
                    / L[((size_t)(b * H_ + h)) * S_ + q0 + 32 * wid + 16 * i + 4 * rgrp + r];

        #pragma unroll
        for (int i = 0; i < 2; ++i)
            #pragma unroll
            for (int n = 0; n < 4; ++n)
                #pragma unroll
                for (int r = 0; r < 4; ++r)
                    macc[i][n][r] = fmaf(exp2f(sacc[i][n][r] * SCL), li[i][r], macc[i][n][r]);
    }

    #pragma unroll
    for (int i = 0; i < 2; ++i)
        #pragma unroll
        for (int n = 0; n < 4; ++n)
            #pragma unroll
            for (int r = 0; r < 4; ++r) {
                int q = q0 + 32 * wid + 16 * i + 4 * rgrp + r;
                attn_out[((size_t)b * S_ + q) * S_ + k0 + 16 * n + col_l] = macc[i][n][r];
            }
}

// ---------------------------------------------------------------------------
// K4a: pooled[b,d] = (1/S) sum_s ctx_unnorm[b,s,d] / l[b, d>>6, s]
// ---------------------------------------------------------------------------
__global__ __launch_bounds__(256) void pool_k(
    const float* __restrict__ CTX, const float* __restrict__ L,
    float* __restrict__ pooled)
{
    const int b = blockIdx.y;
    const int d = blockIdx.x * 256 + threadIdx.x;
    const int h = d >> 6;
    const float* lp = L + ((size_t)(b * H_ + h)) * S_;
    const float* cp = CTX + (size_t)b * S_ * D_ + d;
    float sum = 0.f;
    for (int s = 0; s < S_; ++s)
        sum += cp[(size_t)s * D_] / lp[s];
    pooled[b * D_ + d] = sum * (1.0f / S_);
}

// ---------------------------------------------------------------------------
// K4b: out[b,j] = pooled[b,:] . wo[j,:] + bo[j]   (fp32, tiny)
// ---------------------------------------------------------------------------
__global__ __launch_bounds__(256) void out_k(
    const float* __restrict__ pooled, const float* __restrict__ wo,
    const float* __restrict__ bo, float* __restrict__ out)
{
    __shared__ float psm[D_];
    const int b = blockIdx.x >> 2;
    for (int i = threadIdx.x; i < D_; i += 256) psm[i] = pooled[b * D_ + i];
    __syncthreads();
    const int j = (blockIdx.x & 3) * 256 + threadIdx.x;
    float sum = bo[j];
    const float* wr = wo + (size_t)j * D_;
    for (int d = 0; d < D_; d += 4) {
        float4 w4 = *(const float4*)&wr[d];
        sum += psm[d] * w4.x + psm[d+1] * w4.y + psm[d+2] * w4.z + psm[d+3] * w4.w;
    }
    out[b * D_ + j] = sum;
}

// ---------------------------------------------------------------------------
extern "C" void kernel_launch(void* const* d_in, const int* in_sizes, int n_in,
                              void* d_out, int out_size, void* d_ws, size_t ws_size,
                              hipStream_t stream)
{
    const float* x  = (const float*)d_in[0];
    const float* wq = (const float*)d_in[1];
    const float* bq = (const float*)d_in[2];
    const float* wk = (const float*)d_in[3];
    const float* bk = (const float*)d_in[4];
    const float* wv = (const float*)d_in[5];
    const float* bv = (const float*)d_in[6];
    const float* wo = (const float*)d_in[7];
    const float* bo = (const float*)d_in[8];
    float* out = (float*)d_out;

    char* ws = (char*)d_ws;
    const size_t XN  = (size_t)M_ * D_;            // 8,388,608
    const size_t WN  = (size_t)D_ * D_;            // 1,048,576
    const size_t QN  = (size_t)B_ * H_ * S_ * HD_; // 8,388,608

    unsigned short* xb  = (unsigned short*)ws;                 ws += XN * 2;   // 16 MB
    unsigned short* wqb = (unsigned short*)ws;                 ws += WN * 2;   // 2 MB
    unsigned short* wkb = (unsigned short*)ws;                 ws += WN * 2;
    unsigned short* wvb = (unsigned short*)ws;                 ws += WN * 2;
    unsigned short* Qb  = (unsigned short*)ws;                 ws += QN * 2;   // 16 MB
    unsigned short* Kb  = (unsigned short*)ws;                 ws += QN * 2;
    unsigned short* Vb  = (unsigned short*)ws;                 ws += QN * 2;
    float* Lb   = (float*)ws;                                  ws += (size_t)B_ * H_ * S_ * 4;
    float* CTX  = (float*)ws;                                  ws += XN * 4;   // 32 MB
    float* POOL = (float*)ws;
    // total ~102.5 MB

    cast_k<<<dim3(XN / 1024), 256, 0, stream>>>(x, xb, (int)XN);
    cast_k<<<dim3(WN / 1024), 256, 0, stream>>>(wq, wqb, (int)WN);
    cast_k<<<dim3(WN / 1024), 256, 0, stream>>>(wk, wkb, (int)WN);
    cast_k<<<dim3(WN / 1024), 256, 0, stream>>>(wv, wvb, (int)WN);

    qkv_gemm_k<<<dim3(M_ / 128, D_ / 128, 3), 256, 0, stream>>>(
        xb, wqb, wkb, wvb, bq, bk, bv, Qb, Kb, Vb);
    attn_ctx_k<<<dim3(S_ / 128, H_, B_), 256, 0, stream>>>(Qb, Kb, Vb, Lb, CTX);
    attn_mean_k<<<dim3(S_ / 64, S_ / 128, B_), 256, 0, stream>>>(Qb, Kb, Lb, out + B_ * D_);
    pool_k<<<dim3(D_ / 256, B_), 256, 0, stream>>>(CTX, Lb, POOL);
    out_k<<<16, 256, 0, stream>>>(POOL, wo, bo, out);
}

// Round 3
// 570.242 us; speedup vs baseline: 2.0052x; 2.0052x over previous
//
#include <hip/hip_runtime.h>

#define B_ 4
#define S_ 2048
#define D_ 1024
#define H_ 16
#define HD_ 64
#define M_ 8192  // B_*S_

typedef __attribute__((ext_vector_type(8))) short          bf16x8;
typedef __attribute__((ext_vector_type(8))) unsigned short u16x8;
typedef __attribute__((ext_vector_type(4))) float          f32x4;

#define MFMA16(a, b, c) __builtin_amdgcn_mfma_f32_16x16x32_bf16((a), (b), (c), 0, 0, 0)

// exp(x*0.125) == exp2(x * 0.125*log2(e)); same constant in both passes so
// l (denominator) and the attn-mean numerator stay consistent.
#define SCL 0.18033688011112042f

__device__ __forceinline__ unsigned short f2b(float f) {  // RTNE fp32->bf16
    unsigned int u = __float_as_uint(f);
    return (unsigned short)((u + 0x7fffu + ((u >> 16) & 1u)) >> 16);
}

// ---------------------------------------------------------------------------
// K0: fp32 -> bf16 cast (x and the three weight matrices)
// ---------------------------------------------------------------------------
__global__ __launch_bounds__(256) void cast_k(const float* __restrict__ src,
                                              unsigned short* __restrict__ dst, int n) {
    int i = (blockIdx.x * 256 + threadIdx.x) * 4;
    if (i >= n) return;
    float4 v = *(const float4*)(src + i);
    ushort4 o;
    o.x = f2b(v.x); o.y = f2b(v.y); o.z = f2b(v.z); o.w = f2b(v.w);
    *(ushort4*)(dst + i) = o;
}

// ---------------------------------------------------------------------------
// K1: QKV projection, bf16 MFMA.  y = x @ W.T + b, W row-major [n][k].
// 128x128 tile, BK=64, 4 waves (2x2), 64x64 per wave = 4x4 frags of 16x16.
// Output bf16 in [B][H][S][HD] layout.
// ---------------------------------------------------------------------------
__global__ __launch_bounds__(256) void qkv_gemm_k(
    const unsigned short* __restrict__ xb,
    const unsigned short* __restrict__ wb0, const unsigned short* __restrict__ wb1,
    const unsigned short* __restrict__ wb2,
    const float* __restrict__ bq, const float* __restrict__ bk, const float* __restrict__ bv,
    unsigned short* __restrict__ Qo, unsigned short* __restrict__ Ko,
    unsigned short* __restrict__ Vo)
{
    __shared__ unsigned short xs[128][72];
    __shared__ unsigned short wsm[128][72];

    const unsigned short* W; const float* bias; unsigned short* out;
    if (blockIdx.z == 0)      { W = wb0; bias = bq; out = Qo; }
    else if (blockIdx.z == 1) { W = wb1; bias = bk; out = Ko; }
    else                      { W = wb2; bias = bv; out = Vo; }

    const int m0 = blockIdx.x * 128, n0 = blockIdx.y * 128;
    const int tid = threadIdx.x, lane = tid & 63, wid = tid >> 6;
    const int wm = (wid >> 1) * 64, wn = (wid & 1) * 64;
    const int srow = tid >> 3;          // 0..31
    const int skc  = (tid & 7) * 8;     // bf16 col 0,8,..,56

    f32x4 acc[4][4] = {};

    for (int k0 = 0; k0 < D_; k0 += 64) {
        u16x8 xa[4], wa[4];
        #pragma unroll
        for (int r = 0; r < 4; ++r) {
            int row = srow + 32 * r;
            xa[r] = *(const u16x8*)&xb[(size_t)(m0 + row) * D_ + k0 + skc];
            wa[r] = *(const u16x8*)&W [(size_t)(n0 + row) * D_ + k0 + skc];
        }
        __syncthreads();
        #pragma unroll
        for (int r = 0; r < 4; ++r) {
            int row = srow + 32 * r;
            *(u16x8*)&xs[row][skc]  = xa[r];
            *(u16x8*)&wsm[row][skc] = wa[r];
        }
        __syncthreads();
        #pragma unroll
        for (int kd = 0; kd < 2; ++kd) {
            const int kc = 32 * kd + 8 * (lane >> 4);
            bf16x8 af[4], bfr[4];
            #pragma unroll
            for (int mf = 0; mf < 4; ++mf)
                af[mf] = *(const bf16x8*)&xs[wm + 16 * mf + (lane & 15)][kc];
            #pragma unroll
            for (int nf = 0; nf < 4; ++nf)
                bfr[nf] = *(const bf16x8*)&wsm[wn + 16 * nf + (lane & 15)][kc];
            #pragma unroll
            for (int mf = 0; mf < 4; ++mf)
                #pragma unroll
                for (int nf = 0; nf < 4; ++nf)
                    acc[mf][nf] = MFMA16(af[mf], bfr[nf], acc[mf][nf]);
        }
    }

    const int col_l = lane & 15, rgrp = lane >> 4;
    #pragma unroll
    for (int nf = 0; nf < 4; ++nf) {
        const int n = n0 + wn + 16 * nf + col_l;
        const float bval = bias[n];
        const int h = n >> 6, d = n & 63;
        #pragma unroll
        for (int mf = 0; mf < 4; ++mf)
            #pragma unroll
            for (int r = 0; r < 4; ++r) {
                int m = m0 + wm + 16 * mf + 4 * rgrp + r;
                int bI = m >> 11, s = m & 2047;
                out[(((size_t)bI * H_ + h) * S_ + s) * HD_ + d] = f2b(acc[mf][nf][r] + bval);
            }
    }
}

// ---------------------------------------------------------------------------
// K2: attention pass 1 (bf16 MFMA). Per block: one (b,h), 128 q-rows.
// Q-frags hoisted to registers; K staged linear; V staged transposed;
// P round-trips through wave-private LDS rows. l = sum exp(s/8) (no max
// subtraction: |s| < ~2).  Outputs: L (row sums) and PPOOL (per-q-block
// partial of the pooled mean: sum_q ctx[q,d]/l[q]) — no CTX materialized.
// ---------------------------------------------------------------------------
__global__ __launch_bounds__(256) void attn_ctx_k(
    const unsigned short* __restrict__ Q, const unsigned short* __restrict__ K,
    const unsigned short* __restrict__ V,
    float* __restrict__ L, float* __restrict__ PPOOL)
{
    __shared__ unsigned short ks[64][72];
    __shared__ unsigned short vt[64][72];   // transposed: vt[d][kpos]
    __shared__ unsigned short ps[128][72];  // wave-private row stripes
    __shared__ float pp[4][64];             // per-wave pooled partials

    const int q0 = blockIdx.x * 128, h = blockIdx.y, b = blockIdx.z;
    const size_t hoff = ((size_t)(b * H_ + h)) * S_ * HD_;
    const unsigned short* Qh = Q + hoff;
    const unsigned short* Kh = K + hoff;
    const unsigned short* Vh = V + hoff;

    const int tid = threadIdx.x, lane = tid & 63, wid = tid >> 6;
    const int srow = tid >> 3;       // 0..31
    const int skc  = (tid & 7) * 8;

    bf16x8 qf[2][2];
    #pragma unroll
    for (int i = 0; i < 2; ++i)
        #pragma unroll
        for (int kd = 0; kd < 2; ++kd)
            qf[i][kd] = *(const bf16x8*)&Qh[(size_t)(q0 + 32 * wid + 16 * i + (lane & 15)) * HD_
                                            + 32 * kd + 8 * (lane >> 4)];

    f32x4 cacc[2][4] = {};
    float lp[2][4] = {};

    for (int kb = 0; kb < S_; kb += 64) {
        u16x8 ka[2], va[2];
        #pragma unroll
        for (int r = 0; r < 2; ++r) {
            int row = srow + 32 * r;
            ka[r] = *(const u16x8*)&Kh[(size_t)(kb + row) * HD_ + skc];
            va[r] = *(const u16x8*)&Vh[(size_t)(kb + row) * HD_ + skc];
        }
        __syncthreads();   // everyone done reading previous ks/vt
        #pragma unroll
        for (int r = 0; r < 2; ++r) {
            int row = srow + 32 * r;
            *(u16x8*)&ks[row][skc] = ka[r];
            #pragma unroll
            for (int j = 0; j < 8; ++j)
                vt[skc + j][row] = va[r][j];
        }
        __syncthreads();

        // S = Q K^T  (rows q, cols kpos)
        f32x4 sacc[2][4] = {};
        #pragma unroll
        for (int kd = 0; kd < 2; ++kd) {
            const int kc = 32 * kd + 8 * (lane >> 4);
            bf16x8 kf[4];
            #pragma unroll
            for (int n = 0; n < 4; ++n)
                kf[n] = *(const bf16x8*)&ks[16 * n + (lane & 15)][kc];
            #pragma unroll
            for (int i = 0; i < 2; ++i)
                #pragma unroll
                for (int n = 0; n < 4; ++n)
                    sacc[i][n] = MFMA16(qf[i][kd], kf[n], sacc[i][n]);
        }
        // exp, l-partials, stage P (bf16) into wave-private rows
        #pragma unroll
        for (int i = 0; i < 2; ++i)
            #pragma unroll
            for (int n = 0; n < 4; ++n)
                #pragma unroll
                for (int r = 0; r < 4; ++r) {
                    float e = exp2f(sacc[i][n][r] * SCL);
                    lp[i][r] += e;
                    ps[32 * wid + 16 * i + 4 * (lane >> 4) + r][16 * n + (lane & 15)] = f2b(e);
                }
        // ctx += P @ V   (in-wave ds_write->ds_read ordering handled by compiler)
        #pragma unroll
        for (int kk = 0; kk < 2; ++kk) {
            const int kc = 32 * kk + 8 * (lane >> 4);
            bf16x8 pa[2], vf[4];
            #pragma unroll
            for (int i = 0; i < 2; ++i)
                pa[i] = *(const bf16x8*)&ps[32 * wid + 16 * i + (lane & 15)][kc];
            #pragma unroll
            for (int n = 0; n < 4; ++n)
                vf[n] = *(const bf16x8*)&vt[16 * n + (lane & 15)][kc];
            #pragma unroll
            for (int i = 0; i < 2; ++i)
                #pragma unroll
                for (int n = 0; n < 4; ++n)
                    cacc[i][n] = MFMA16(pa[i], vf[n], cacc[i][n]);
        }
    }

    // reduce l across the 16 column-lanes of each row group
    #pragma unroll
    for (int i = 0; i < 2; ++i)
        #pragma unroll
        for (int r = 0; r < 4; ++r) {
            float v = lp[i][r];
            v += __shfl_xor(v, 1); v += __shfl_xor(v, 2);
            v += __shfl_xor(v, 4); v += __shfl_xor(v, 8);
            lp[i][r] = v;
        }
    if ((lane & 15) == 0) {
        #pragma unroll
        for (int i = 0; i < 2; ++i)
            #pragma unroll
            for (int r = 0; r < 4; ++r)
                L[((size_t)(b * H_ + h)) * S_ + q0 + 32 * wid + 16 * i + 4 * (lane >> 4) + r]
                    = lp[i][r];
    }

    // pooled partial: sum over this wave's 32 q-rows of cacc/l, per head-dim.
    float pool4[4] = {};
    #pragma unroll
    for (int i = 0; i < 2; ++i)
        #pragma unroll
        for (int r = 0; r < 4; ++r) {
            float inv = 1.0f / lp[i][r];
            #pragma unroll
            for (int n = 0; n < 4; ++n)
                pool4[n] = fmaf(cacc[i][n][r], inv, pool4[n]);
        }
    #pragma unroll
    for (int n = 0; n < 4; ++n) {
        float v = pool4[n];
        v += __shfl_xor(v, 16); v += __shfl_xor(v, 32);  // sum over rgrp lanes
        pool4[n] = v;
    }
    if (lane < 16) {
        #pragma unroll
        for (int n = 0; n < 4; ++n) pp[wid][16 * n + lane] = pool4[n];
    }
    __syncthreads();
    if (tid < 64) {
        float s = pp[0][tid] + pp[1][tid] + pp[2][tid] + pp[3][tid];
        PPOOL[((size_t)(b * H_ + h) * (S_ / 128) + blockIdx.x) * 64 + tid] = s;
    }
}

// ---------------------------------------------------------------------------
// K3: attn_mean[b,q,k] = (1/16) sum_h exp(s_h/8)/l_h — second score pass,
// MFMA, no LDS: fragments loaded straight from global (L2/L3-resident).
// Block: 128 q-rows x 64 k-cols, loop over 16 heads.
// ---------------------------------------------------------------------------
__global__ __launch_bounds__(256) void attn_mean_k(
    const unsigned short* __restrict__ Q, const unsigned short* __restrict__ K,
    const float* __restrict__ L, float* __restrict__ attn_out)
{
    const int k0 = blockIdx.x * 64, q0 = blockIdx.y * 128, b = blockIdx.z;
    const int lane = threadIdx.x & 63, wid = threadIdx.x >> 6;
    const int rgrp = lane >> 4, col_l = lane & 15;

    f32x4 macc[2][4] = {};

    for (int h = 0; h < H_; ++h) {
        const size_t hoff = ((size_t)(b * H_ + h)) * S_ * HD_;
        const unsigned short* Qh = Q + hoff;
        const unsigned short* Kh = K + hoff;

        bf16x8 qf[2][2], kf[4][2];
        #pragma unroll
        for (int i = 0; i < 2; ++i)
            #pragma unroll
            for (int kd = 0; kd < 2; ++kd)
                qf[i][kd] = *(const bf16x8*)&Qh[(size_t)(q0 + 32 * wid + 16 * i + col_l) * HD_
                                                + 32 * kd + 8 * rgrp];
        #pragma unroll
        for (int n = 0; n < 4; ++n)
            #pragma unroll
            for (int kd = 0; kd < 2; ++kd)
                kf[n][kd] = *(const bf16x8*)&Kh[(size_t)(k0 + 16 * n + col_l) * HD_
                                                + 32 * kd + 8 * rgrp];

        f32x4 sacc[2][4] = {};
        #pragma unroll
        for (int kd = 0; kd < 2; ++kd)
            #pragma unroll
            for (int i = 0; i < 2; ++i)
                #pragma unroll
                for (int n = 0; n < 4; ++n)
                    sacc[i][n] = MFMA16(qf[i][kd], kf[n][kd], sacc[i][n]);

        float li[2][4];
        #pragma unroll
        for (int i = 0; i < 2; ++i)
            #pragma unroll
            for (int r = 0; r < 4; ++r)
                li[i][r] = 0.0625f
                    / L[((size_t)(b * H_ + h)) * S_ + q0 + 32 * wid + 16 * i + 4 * rgrp + r];

        #pragma unroll
        for (int i = 0; i < 2; ++i)
            #pragma unroll
            for (int n = 0; n < 4; ++n)
                #pragma unroll
                for (int r = 0; r < 4; ++r)
                    macc[i][n][r] = fmaf(exp2f(sacc[i][n][r] * SCL), li[i][r], macc[i][n][r]);
    }

    #pragma unroll
    for (int i = 0; i < 2; ++i)
        #pragma unroll
        for (int n = 0; n < 4; ++n)
            #pragma unroll
            for (int r = 0; r < 4; ++r) {
                int q = q0 + 32 * wid + 16 * i + 4 * rgrp + r;
                attn_out[((size_t)b * S_ + q) * S_ + k0 + 16 * n + col_l] = macc[i][n][r];
            }
}

// ---------------------------------------------------------------------------
// K4: out[b,j] = pooled[b,:] . wo[j,:] + bo[j], with pooled reduced from
// PPOOL partials in-block (16 q-block partials per (b,h)).
// ---------------------------------------------------------------------------
__global__ __launch_bounds__(256) void out_k(
    const float* __restrict__ PPOOL, const float* __restrict__ wo,
    const float* __restrict__ bo, float* __restrict__ out)
{
    __shared__ float psm[D_];
    const int b = blockIdx.x >> 2;
    for (int d = threadIdx.x; d < D_; d += 256) {
        const float* pp = PPOOL + ((size_t)(b * H_ + (d >> 6)) * (S_ / 128)) * 64 + (d & 63);
        float s = 0.f;
        #pragma unroll
        for (int qb = 0; qb < S_ / 128; ++qb) s += pp[qb * 64];
        psm[d] = s * (1.0f / S_);
    }
    __syncthreads();
    const int j = (blockIdx.x & 3) * 256 + threadIdx.x;
    float sum = bo[j];
    const float* wr = wo + (size_t)j * D_;
    for (int d = 0; d < D_; d += 4) {
        float4 w4 = *(const float4*)&wr[d];
        sum += psm[d] * w4.x + psm[d+1] * w4.y + psm[d+2] * w4.z + psm[d+3] * w4.w;
    }
    out[b * D_ + j] = sum;
}

// ---------------------------------------------------------------------------
extern "C" void kernel_launch(void* const* d_in, const int* in_sizes, int n_in,
                              void* d_out, int out_size, void* d_ws, size_t ws_size,
                              hipStream_t stream)
{
    const float* x  = (const float*)d_in[0];
    const float* wq = (const float*)d_in[1];
    const float* bq = (const float*)d_in[2];
    const float* wk = (const float*)d_in[3];
    const float* bk = (const float*)d_in[4];
    const float* wv = (const float*)d_in[5];
    const float* bv = (const float*)d_in[6];
    const float* wo = (const float*)d_in[7];
    const float* bo = (const float*)d_in[8];
    float* out = (float*)d_out;

    char* ws = (char*)d_ws;
    const size_t XN  = (size_t)M_ * D_;            // 8,388,608
    const size_t WN  = (size_t)D_ * D_;            // 1,048,576
    const size_t QN  = (size_t)B_ * H_ * S_ * HD_; // 8,388,608

    unsigned short* xb  = (unsigned short*)ws;                 ws += XN * 2;   // 16 MB
    unsigned short* wqb = (unsigned short*)ws;                 ws += WN * 2;   // 2 MB
    unsigned short* wkb = (unsigned short*)ws;                 ws += WN * 2;
    unsigned short* wvb = (unsigned short*)ws;                 ws += WN * 2;
    unsigned short* Qb  = (unsigned short*)ws;                 ws += QN * 2;   // 16 MB
    unsigned short* Kb  = (unsigned short*)ws;                 ws += QN * 2;
    unsigned short* Vb  = (unsigned short*)ws;                 ws += QN * 2;
    float* Lb    = (float*)ws;                                 ws += (size_t)B_ * H_ * S_ * 4;
    float* PPOOL = (float*)ws;   // B*H*(S/128)*64 = 65536 floats = 256 KB
    // total ~71 MB

    cast_k<<<dim3(XN / 1024), 256, 0, stream>>>(x, xb, (int)XN);
    cast_k<<<dim3(WN / 1024), 256, 0, stream>>>(wq, wqb, (int)WN);
    cast_k<<<dim3(WN / 1024), 256, 0, stream>>>(wk, wkb, (int)WN);
    cast_k<<<dim3(WN / 1024), 256, 0, stream>>>(wv, wvb, (int)WN);

    qkv_gemm_k<<<dim3(M_ / 128, D_ / 128, 3), 256, 0, stream>>>(
        xb, wqb, wkb, wvb, bq, bk, bv, Qb, Kb, Vb);
    attn_ctx_k<<<dim3(S_ / 128, H_, B_), 256, 0, stream>>>(Qb, Kb, Vb, Lb, PPOOL);
    attn_mean_k<<<dim3(S_ / 64, S_ / 128, B_), 256, 0, stream>>>(Qb, Kb, Lb, out + B_ * D_);
    out_k<<<16, 256, 0, stream>>>(PPOOL, wo, bo, out);
}

// Round 4
// 438.196 us; speedup vs baseline: 2.6095x; 1.3013x over previous
//
#include <hip/hip_runtime.h>

#define B_ 4
#define S_ 2048
#define D_ 1024
#define H_ 16
#define HD_ 64
#define M_ 8192  // B_*S_

typedef __attribute__((ext_vector_type(8))) short          bf16x8;
typedef __attribute__((ext_vector_type(8))) unsigned short u16x8;
typedef __attribute__((ext_vector_type(4))) float          f32x4;

#define MFMA16(a, b, c) __builtin_amdgcn_mfma_f32_16x16x32_bf16((a), (b), (c), 0, 0, 0)

// exp(s/8) = exp2(s * 0.125*log2(e)).  SCL is folded into Q at projection
// time, so both attention passes compute exp2(s') directly and stay
// mutually consistent (l and the attn numerator use the same s').
#define SCL 0.18033688011112042f

__device__ __forceinline__ unsigned short f2b(float f) {  // RTNE fp32->bf16
    unsigned int u = __float_as_uint(f);
    return (unsigned short)((u + 0x7fffu + ((u >> 16) & 1u)) >> 16);
}

__device__ __forceinline__ unsigned int cvtpk_bf16(float lo, float hi) {
    unsigned int r;
    asm("v_cvt_pk_bf16_f32 %0, %1, %2" : "=v"(r) : "v"(lo), "v"(hi));
    return r;  // low u16 = bf16(lo), high u16 = bf16(hi)  (RTNE)
}

// ---------------------------------------------------------------------------
// K0: fp32 -> bf16 casts.  cast_k for x; cast3_k for the 3 weight matrices.
// ---------------------------------------------------------------------------
__global__ __launch_bounds__(256) void cast_k(const float* __restrict__ src,
                                              unsigned short* __restrict__ dst, int n) {
    int i = (blockIdx.x * 256 + threadIdx.x) * 4;
    if (i >= n) return;
    float4 v = *(const float4*)(src + i);
    ushort4 o;
    o.x = f2b(v.x); o.y = f2b(v.y); o.z = f2b(v.z); o.w = f2b(v.w);
    *(ushort4*)(dst + i) = o;
}

__global__ __launch_bounds__(256) void cast3_k(
    const float* __restrict__ s0, const float* __restrict__ s1, const float* __restrict__ s2,
    unsigned short* __restrict__ d0, unsigned short* __restrict__ d1,
    unsigned short* __restrict__ d2, int n) {
    const float* src = (blockIdx.y == 0) ? s0 : (blockIdx.y == 1) ? s1 : s2;
    unsigned short* dst = (blockIdx.y == 0) ? d0 : (blockIdx.y == 1) ? d1 : d2;
    int i = (blockIdx.x * 256 + threadIdx.x) * 4;
    if (i >= n) return;
    float4 v = *(const float4*)(src + i);
    ushort4 o;
    o.x = f2b(v.x); o.y = f2b(v.y); o.z = f2b(v.z); o.w = f2b(v.w);
    *(ushort4*)(dst + i) = o;
}

// ---------------------------------------------------------------------------
// K1: QKV projection, bf16 MFMA.  y = x @ W.T + b, W row-major [n][k].
// 128x128 tile, BK=64, 4 waves (2x2), 64x64 per wave = 4x4 frags of 16x16.
// Q output is PRE-SCALED by SCL.  Output bf16 in [B][H][S][HD] layout.
// ---------------------------------------------------------------------------
__global__ __launch_bounds__(256) void qkv_gemm_k(
    const unsigned short* __restrict__ xb,
    const unsigned short* __restrict__ wb0, const unsigned short* __restrict__ wb1,
    const unsigned short* __restrict__ wb2,
    const float* __restrict__ bq, const float* __restrict__ bk, const float* __restrict__ bv,
    unsigned short* __restrict__ Qo, unsigned short* __restrict__ Ko,
    unsigned short* __restrict__ Vo)
{
    __shared__ unsigned short xs[128][72];
    __shared__ unsigned short wsm[128][72];

    const unsigned short* W; const float* bias; unsigned short* out;
    if (blockIdx.z == 0)      { W = wb0; bias = bq; out = Qo; }
    else if (blockIdx.z == 1) { W = wb1; bias = bk; out = Ko; }
    else                      { W = wb2; bias = bv; out = Vo; }
    const float oscale = (blockIdx.z == 0) ? SCL : 1.0f;

    const int m0 = blockIdx.x * 128, n0 = blockIdx.y * 128;
    const int tid = threadIdx.x, lane = tid & 63, wid = tid >> 6;
    const int wm = (wid >> 1) * 64, wn = (wid & 1) * 64;
    const int srow = tid >> 3;          // 0..31
    const int skc  = (tid & 7) * 8;     // bf16 col 0,8,..,56

    f32x4 acc[4][4] = {};

    for (int k0 = 0; k0 < D_; k0 += 64) {
        u16x8 xa[4], wa[4];
        #pragma unroll
        for (int r = 0; r < 4; ++r) {
            int row = srow + 32 * r;
            xa[r] = *(const u16x8*)&xb[(size_t)(m0 + row) * D_ + k0 + skc];
            wa[r] = *(const u16x8*)&W [(size_t)(n0 + row) * D_ + k0 + skc];
        }
        __syncthreads();
        #pragma unroll
        for (int r = 0; r < 4; ++r) {
            int row = srow + 32 * r;
            *(u16x8*)&xs[row][skc]  = xa[r];
            *(u16x8*)&wsm[row][skc] = wa[r];
        }
        __syncthreads();
        #pragma unroll
        for (int kd = 0; kd < 2; ++kd) {
            const int kc = 32 * kd + 8 * (lane >> 4);
            bf16x8 af[4], bfr[4];
            #pragma unroll
            for (int mf = 0; mf < 4; ++mf)
                af[mf] = *(const bf16x8*)&xs[wm + 16 * mf + (lane & 15)][kc];
            #pragma unroll
            for (int nf = 0; nf < 4; ++nf)
                bfr[nf] = *(const bf16x8*)&wsm[wn + 16 * nf + (lane & 15)][kc];
            #pragma unroll
            for (int mf = 0; mf < 4; ++mf)
                #pragma unroll
                for (int nf = 0; nf < 4; ++nf)
                    acc[mf][nf] = MFMA16(af[mf], bfr[nf], acc[mf][nf]);
        }
    }

    const int col_l = lane & 15, rgrp = lane >> 4;
    #pragma unroll
    for (int nf = 0; nf < 4; ++nf) {
        const int n = n0 + wn + 16 * nf + col_l;
        const float bval = bias[n];
        const int h = n >> 6, d = n & 63;
        #pragma unroll
        for (int mf = 0; mf < 4; ++mf)
            #pragma unroll
            for (int r = 0; r < 4; ++r) {
                int m = m0 + wm + 16 * mf + 4 * rgrp + r;
                int bI = m >> 11, s = m & 2047;
                out[(((size_t)bI * H_ + h) * S_ + s) * HD_ + d]
                    = f2b((acc[mf][nf][r] + bval) * oscale);
            }
    }
}

// ---------------------------------------------------------------------------
// K2: attention pass 1 (bf16 MFMA).  Per block: one (b,h), 128 q-rows.
// Swapped QK^T: sacc = mfma(K,Q) so each lane holds 4 CONSECUTIVE k for one
// q -> P-staging is cvt_pk_bf16 pairs + ds_write_b64.  l = sum exp2(s') (no
// max subtraction; Q pre-scaled).  Outputs L and PPOOL (pooled partials).
// ---------------------------------------------------------------------------
__global__ __launch_bounds__(256) void attn_ctx_k(
    const unsigned short* __restrict__ Q, const unsigned short* __restrict__ K,
    const unsigned short* __restrict__ V,
    float* __restrict__ L, float* __restrict__ PPOOL)
{
    __shared__ unsigned short ks[64][72];
    __shared__ unsigned short vt[64][72];   // transposed: vt[d][kpos]
    __shared__ unsigned short ps[128][72];  // P, wave-private row stripes
    __shared__ float pp[4][64];             // per-wave pooled partials
    __shared__ float lsm[4][32];            // per-wave l by local q-row

    const int q0 = blockIdx.x * 128, h = blockIdx.y, b = blockIdx.z;
    const size_t hoff = ((size_t)(b * H_ + h)) * S_ * HD_;
    const unsigned short* Qh = Q + hoff;
    const unsigned short* Kh = K + hoff;
    const unsigned short* Vh = V + hoff;

    const int tid = threadIdx.x, lane = tid & 63, wid = tid >> 6;
    const int srow = tid >> 3;       // 0..31
    const int skc  = (tid & 7) * 8;
    const int col_l = lane & 15, rgrp = lane >> 4;

    bf16x8 qf[2][2];
    #pragma unroll
    for (int i = 0; i < 2; ++i)
        #pragma unroll
        for (int kd = 0; kd < 2; ++kd)
            qf[i][kd] = *(const bf16x8*)&Qh[(size_t)(q0 + 32 * wid + 16 * i + col_l) * HD_
                                            + 32 * kd + 8 * rgrp];

    f32x4 cacc[2][4] = {};
    float lp[2] = {};

    for (int kb = 0; kb < S_; kb += 64) {
        u16x8 ka[2], va[2];
        #pragma unroll
        for (int r = 0; r < 2; ++r) {
            int row = srow + 32 * r;
            ka[r] = *(const u16x8*)&Kh[(size_t)(kb + row) * HD_ + skc];
            va[r] = *(const u16x8*)&Vh[(size_t)(kb + row) * HD_ + skc];
        }
        __syncthreads();   // everyone done reading previous ks/vt
        #pragma unroll
        for (int r = 0; r < 2; ++r) {
            int row = srow + 32 * r;
            *(u16x8*)&ks[row][skc] = ka[r];
            #pragma unroll
            for (int j = 0; j < 8; ++j)
                vt[skc + j][row] = va[r][j];
        }
        __syncthreads();

        // S^T = K Q^T per n-block of 16 k-rows; exp; pack; stage to ps
        #pragma unroll
        for (int n = 0; n < 4; ++n) {
            f32x4 s0 = {}, s1 = {};
            #pragma unroll
            for (int kd = 0; kd < 2; ++kd) {
                const int kc = 32 * kd + 8 * rgrp;
                bf16x8 kf = *(const bf16x8*)&ks[16 * n + col_l][kc];
                s0 = MFMA16(kf, qf[0][kd], s0);
                s1 = MFMA16(kf, qf[1][kd], s1);
            }
            float e0 = exp2f(s0[0]), e1 = exp2f(s0[1]), e2 = exp2f(s0[2]), e3 = exp2f(s0[3]);
            lp[0] += (e0 + e1) + (e2 + e3);
            uint2 w0 = { cvtpk_bf16(e0, e1), cvtpk_bf16(e2, e3) };
            *(uint2*)&ps[32 * wid + col_l][16 * n + 4 * rgrp] = w0;
            float f0 = exp2f(s1[0]), f1 = exp2f(s1[1]), f2 = exp2f(s1[2]), f3 = exp2f(s1[3]);
            lp[1] += (f0 + f1) + (f2 + f3);
            uint2 w1 = { cvtpk_bf16(f0, f1), cvtpk_bf16(f2, f3) };
            *(uint2*)&ps[32 * wid + 16 + col_l][16 * n + 4 * rgrp] = w1;
        }

        // ctx += P @ V  (same-wave LDS RAW; compiler inserts lgkmcnt)
        #pragma unroll
        for (int kk = 0; kk < 2; ++kk) {
            const int kc = 32 * kk + 8 * rgrp;
            bf16x8 pa[2], vf[4];
            #pragma unroll
            for (int i = 0; i < 2; ++i)
                pa[i] = *(const bf16x8*)&ps[32 * wid + 16 * i + col_l][kc];
            #pragma unroll
            for (int n = 0; n < 4; ++n)
                vf[n] = *(const bf16x8*)&vt[16 * n + col_l][kc];
            #pragma unroll
            for (int i = 0; i < 2; ++i)
                #pragma unroll
                for (int n = 0; n < 4; ++n)
                    cacc[i][n] = MFMA16(pa[i], vf[n], cacc[i][n]);
        }
    }

    // reduce l over the 4 rgrp lane groups (each holds a disjoint k-subset)
    #pragma unroll
    for (int i = 0; i < 2; ++i) {
        float v = lp[i];
        v += __shfl_xor(v, 16); v += __shfl_xor(v, 32);
        lp[i] = v;
    }
    if (lane < 16) {
        #pragma unroll
        for (int i = 0; i < 2; ++i) {
            L[((size_t)(b * H_ + h)) * S_ + q0 + 32 * wid + 16 * i + lane] = lp[i];
            lsm[wid][16 * i + lane] = lp[i];
        }
    }

    // pooled partial: sum over this wave's 32 q-rows of cacc/l, per head-dim
    float pool4[4] = {};
    #pragma unroll
    for (int i = 0; i < 2; ++i)
        #pragma unroll
        for (int r = 0; r < 4; ++r) {
            float inv = 1.0f / lsm[wid][16 * i + 4 * rgrp + r];
            #pragma unroll
            for (int n = 0; n < 4; ++n)
                pool4[n] = fmaf(cacc[i][n][r], inv, pool4[n]);
        }
    #pragma unroll
    for (int n = 0; n < 4; ++n) {
        float v = pool4[n];
        v += __shfl_xor(v, 16); v += __shfl_xor(v, 32);
        pool4[n] = v;
    }
    if (lane < 16) {
        #pragma unroll
        for (int n = 0; n < 4; ++n) pp[wid][16 * n + lane] = pool4[n];
    }
    __syncthreads();
    if (tid < 64) {
        float s = pp[0][tid] + pp[1][tid] + pp[2][tid] + pp[3][tid];
        PPOOL[((size_t)(b * H_ + h) * (S_ / 128) + blockIdx.x) * 64 + tid] = s;
    }
}

// ---------------------------------------------------------------------------
// K3: attn_mean[b,q,k] = (1/16) sum_h exp2(s'_h)/l_h — second score pass.
// LDS-staged Q (128x64) and K (64x64) tiles per head; swapped MFMA so the
// epilogue is dwordx4 stores and l is loaded twice (not 8x) per head.
// ---------------------------------------------------------------------------
__global__ __launch_bounds__(256) void attn_mean_k(
    const unsigned short* __restrict__ Q, const unsigned short* __restrict__ K,
    const float* __restrict__ L, float* __restrict__ attn_out)
{
    __shared__ unsigned short qs[128][72];
    __shared__ unsigned short ksm[64][72];
    __shared__ float lsm[128];

    const int k0 = blockIdx.x * 64, q0 = blockIdx.y * 128, b = blockIdx.z;
    const int tid = threadIdx.x, lane = tid & 63, wid = tid >> 6;
    const int col_l = lane & 15, rgrp = lane >> 4;
    const int qrow = tid >> 1, qcol = (tid & 1) * 32;   // Q staging: 32 elems/thread
    const int krow = tid >> 2, kcol = (tid & 3) * 16;   // K staging: 16 elems/thread

    f32x4 macc[4][2] = {};   // [n: k-16-block][i: q-16-block]

    for (int h = 0; h < H_; ++h) {
        const size_t hoff = ((size_t)(b * H_ + h)) * S_ * HD_;
        const unsigned short* Qh = Q + hoff;
        const unsigned short* Kh = K + hoff;

        u16x8 qa[4], ka[2];
        #pragma unroll
        for (int j = 0; j < 4; ++j)
            qa[j] = *(const u16x8*)&Qh[(size_t)(q0 + qrow) * HD_ + qcol + 8 * j];
        #pragma unroll
        for (int j = 0; j < 2; ++j)
            ka[j] = *(const u16x8*)&Kh[(size_t)(k0 + krow) * HD_ + kcol + 8 * j];
        float lval = 0.f;
        if (tid < 128) lval = L[((size_t)(b * H_ + h)) * S_ + q0 + tid];

        __syncthreads();   // previous head's compute done
        #pragma unroll
        for (int j = 0; j < 4; ++j) *(u16x8*)&qs[qrow][qcol + 8 * j] = qa[j];
        #pragma unroll
        for (int j = 0; j < 2; ++j) *(u16x8*)&ksm[krow][kcol + 8 * j] = ka[j];
        if (tid < 128) lsm[tid] = lval;
        __syncthreads();

        bf16x8 qf[2][2];
        #pragma unroll
        for (int i = 0; i < 2; ++i)
            #pragma unroll
            for (int kd = 0; kd < 2; ++kd)
                qf[i][kd] = *(const bf16x8*)&qs[32 * wid + 16 * i + col_l][32 * kd + 8 * rgrp];

        float li0 = 0.0625f / lsm[32 * wid + col_l];
        float li1 = 0.0625f / lsm[32 * wid + 16 + col_l];

        #pragma unroll
        for (int n = 0; n < 4; ++n) {
            f32x4 s0 = {}, s1 = {};
            #pragma unroll
            for (int kd = 0; kd < 2; ++kd) {
                bf16x8 kf = *(const bf16x8*)&ksm[16 * n + col_l][32 * kd + 8 * rgrp];
                s0 = MFMA16(kf, qf[0][kd], s0);
                s1 = MFMA16(kf, qf[1][kd], s1);
            }
            #pragma unroll
            for (int r = 0; r < 4; ++r) {
                macc[n][0][r] = fmaf(exp2f(s0[r]), li0, macc[n][0][r]);
                macc[n][1][r] = fmaf(exp2f(s1[r]), li1, macc[n][1][r]);
            }
        }
    }

    #pragma unroll
    for (int n = 0; n < 4; ++n)
        #pragma unroll
        for (int i = 0; i < 2; ++i) {
            int q = q0 + 32 * wid + 16 * i + col_l;
            *(f32x4*)&attn_out[((size_t)b * S_ + q) * S_ + k0 + 16 * n + 4 * rgrp]
                = macc[n][i];
        }
}

// ---------------------------------------------------------------------------
// K4: out[b,j] = pooled[b,:] . wo[j,:] + bo[j], pooled reduced from PPOOL.
// ---------------------------------------------------------------------------
__global__ __launch_bounds__(256) void out_k(
    const float* __restrict__ PPOOL, const float* __restrict__ wo,
    const float* __restrict__ bo, float* __restrict__ out)
{
    __shared__ float psm[D_];
    const int b = blockIdx.x >> 2;
    for (int d = threadIdx.x; d < D_; d += 256) {
        const float* pp = PPOOL + ((size_t)(b * H_ + (d >> 6)) * (S_ / 128)) * 64 + (d & 63);
        float s = 0.f;
        #pragma unroll
        for (int qb = 0; qb < S_ / 128; ++qb) s += pp[qb * 64];
        psm[d] = s * (1.0f / S_);
    }
    __syncthreads();
    const int j = (blockIdx.x & 3) * 256 + threadIdx.x;
    float sum = bo[j];
    const float* wr = wo + (size_t)j * D_;
    for (int d = 0; d < D_; d += 4) {
        float4 w4 = *(const float4*)&wr[d];
        sum += psm[d] * w4.x + psm[d+1] * w4.y + psm[d+2] * w4.z + psm[d+3] * w4.w;
    }
    out[b * D_ + j] = sum;
}

// ---------------------------------------------------------------------------
extern "C" void kernel_launch(void* const* d_in, const int* in_sizes, int n_in,
                              void* d_out, int out_size, void* d_ws, size_t ws_size,
                              hipStream_t stream)
{
    const float* x  = (const float*)d_in[0];
    const float* wq = (const float*)d_in[1];
    const float* bq = (const float*)d_in[2];
    const float* wk = (const float*)d_in[3];
    const float* bk = (const float*)d_in[4];
    const float* wv = (const float*)d_in[5];
    const float* bv = (const float*)d_in[6];
    const float* wo = (const float*)d_in[7];
    const float* bo = (const float*)d_in[8];
    float* out = (float*)d_out;

    char* ws = (char*)d_ws;
    const size_t XN  = (size_t)M_ * D_;            // 8,388,608
    const size_t WN  = (size_t)D_ * D_;            // 1,048,576
    const size_t QN  = (size_t)B_ * H_ * S_ * HD_; // 8,388,608

    unsigned short* xb  = (unsigned short*)ws;                 ws += XN * 2;   // 16 MB
    unsigned short* wqb = (unsigned short*)ws;                 ws += WN * 2;   // 2 MB
    unsigned short* wkb = (unsigned short*)ws;                 ws += WN * 2;
    unsigned short* wvb = (unsigned short*)ws;                 ws += WN * 2;
    unsigned short* Qb  = (unsigned short*)ws;                 ws += QN * 2;   // 16 MB
    unsigned short* Kb  = (unsigned short*)ws;                 ws += QN * 2;
    unsigned short* Vb  = (unsigned short*)ws;                 ws += QN * 2;
    float* Lb    = (float*)ws;                                 ws += (size_t)B_ * H_ * S_ * 4;
    float* PPOOL = (float*)ws;   // B*H*(S/128)*64 = 65536 floats = 256 KB

    cast_k<<<dim3(XN / 1024), 256, 0, stream>>>(x, xb, (int)XN);
    cast3_k<<<dim3(WN / 1024, 3), 256, 0, stream>>>(wq, wk, wv, wqb, wkb, wvb, (int)WN);

    qkv_gemm_k<<<dim3(M_ / 128, D_ / 128, 3), 256, 0, stream>>>(
        xb, wqb, wkb, wvb, bq, bk, bv, Qb, Kb, Vb);
    attn_ctx_k<<<dim3(S_ / 128, H_, B_), 256, 0, stream>>>(Qb, Kb, Vb, Lb, PPOOL);
    attn_mean_k<<<dim3(S_ / 64, S_ / 128, B_), 256, 0, stream>>>(Qb, Kb, Lb, out + B_ * D_);
    out_k<<<16, 256, 0, stream>>>(PPOOL, wo, bo, out);
}

// Round 5
// 404.129 us; speedup vs baseline: 2.8294x; 1.0843x over previous
//
#include <hip/hip_runtime.h>

#define B_ 4
#define S_ 2048
#define D_ 1024
#define H_ 16
#define HD_ 64
#define M_ 8192  // B_*S_

typedef __attribute__((ext_vector_type(8))) short          bf16x8;
typedef __attribute__((ext_vector_type(8))) unsigned short u16x8;
typedef __attribute__((ext_vector_type(4))) float          f32x4;

#define MFMA16(a, b, c) __builtin_amdgcn_mfma_f32_16x16x32_bf16((a), (b), (c), 0, 0, 0)

// exp(s/8) = exp2(s * 0.125*log2(e)).  SCL is folded into Q at projection
// time, so both attention passes compute exp2(s') directly and stay
// mutually consistent (l and the attn numerator use the same s').
#define SCL 0.18033688011112042f

__device__ __forceinline__ unsigned short f2b(float f) {  // RTNE fp32->bf16
    unsigned int u = __float_as_uint(f);
    return (unsigned short)((u + 0x7fffu + ((u >> 16) & 1u)) >> 16);
}

__device__ __forceinline__ unsigned int cvtpk_bf16(float lo, float hi) {
    unsigned int r;
    asm("v_cvt_pk_bf16_f32 %0, %1, %2" : "=v"(r) : "v"(lo), "v"(hi));
    return r;  // low u16 = bf16(lo), high u16 = bf16(hi)  (RTNE)
}

// ---------------------------------------------------------------------------
// K0: fp32 -> bf16 casts.  cast_k for x; cast3_k for the 3 weight matrices.
// ---------------------------------------------------------------------------
__global__ __launch_bounds__(256) void cast_k(const float* __restrict__ src,
                                              unsigned short* __restrict__ dst, int n) {
    int i = (blockIdx.x * 256 + threadIdx.x) * 4;
    if (i >= n) return;
    float4 v = *(const float4*)(src + i);
    ushort4 o;
    o.x = f2b(v.x); o.y = f2b(v.y); o.z = f2b(v.z); o.w = f2b(v.w);
    *(ushort4*)(dst + i) = o;
}

__global__ __launch_bounds__(256) void cast3_k(
    const float* __restrict__ s0, const float* __restrict__ s1, const float* __restrict__ s2,
    unsigned short* __restrict__ d0, unsigned short* __restrict__ d1,
    unsigned short* __restrict__ d2, int n) {
    const float* src = (blockIdx.y == 0) ? s0 : (blockIdx.y == 1) ? s1 : s2;
    unsigned short* dst = (blockIdx.y == 0) ? d0 : (blockIdx.y == 1) ? d1 : d2;
    int i = (blockIdx.x * 256 + threadIdx.x) * 4;
    if (i >= n) return;
    float4 v = *(const float4*)(src + i);
    ushort4 o;
    o.x = f2b(v.x); o.y = f2b(v.y); o.z = f2b(v.z); o.w = f2b(v.w);
    *(ushort4*)(dst + i) = o;
}

// ---------------------------------------------------------------------------
// K1: QKV projection, bf16 MFMA.  y = x @ W.T + b, W row-major [n][k].
// 128x128 tile, BK=64, 4 waves (2x2), 64x64 per wave = 4x4 frags of 16x16.
// Q output PRE-SCALED by SCL, layout [B][H][S][HD].  K layout [B][H][S][HD].
// V written TRANSPOSED: VT[B][H][HD][S] (lane holds 4 consecutive s for a
// fixed d -> one ushort4 store per fragment; also kills the LDS transpose
// in attn_ctx_k).
// ---------------------------------------------------------------------------
__global__ __launch_bounds__(256) void qkv_gemm_k(
    const unsigned short* __restrict__ xb,
    const unsigned short* __restrict__ wb0, const unsigned short* __restrict__ wb1,
    const unsigned short* __restrict__ wb2,
    const float* __restrict__ bq, const float* __restrict__ bk, const float* __restrict__ bv,
    unsigned short* __restrict__ Qo, unsigned short* __restrict__ Ko,
    unsigned short* __restrict__ VT)
{
    __shared__ unsigned short xs[128][72];
    __shared__ unsigned short wsm[128][72];

    const unsigned short* W; const float* bias;
    if (blockIdx.z == 0)      { W = wb0; bias = bq; }
    else if (blockIdx.z == 1) { W = wb1; bias = bk; }
    else                      { W = wb2; bias = bv; }

    const int m0 = blockIdx.x * 128, n0 = blockIdx.y * 128;
    const int tid = threadIdx.x, lane = tid & 63, wid = tid >> 6;
    const int wm = (wid >> 1) * 64, wn = (wid & 1) * 64;
    const int srow = tid >> 3;          // 0..31
    const int skc  = (tid & 7) * 8;     // bf16 col 0,8,..,56

    f32x4 acc[4][4] = {};

    for (int k0 = 0; k0 < D_; k0 += 64) {
        u16x8 xa[4], wa[4];
        #pragma unroll
        for (int r = 0; r < 4; ++r) {
            int row = srow + 32 * r;
            xa[r] = *(const u16x8*)&xb[(size_t)(m0 + row) * D_ + k0 + skc];
            wa[r] = *(const u16x8*)&W [(size_t)(n0 + row) * D_ + k0 + skc];
        }
        __syncthreads();
        #pragma unroll
        for (int r = 0; r < 4; ++r) {
            int row = srow + 32 * r;
            *(u16x8*)&xs[row][skc]  = xa[r];
            *(u16x8*)&wsm[row][skc] = wa[r];
        }
        __syncthreads();
        #pragma unroll
        for (int kd = 0; kd < 2; ++kd) {
            const int kc = 32 * kd + 8 * (lane >> 4);
            bf16x8 af[4], bfr[4];
            #pragma unroll
            for (int mf = 0; mf < 4; ++mf)
                af[mf] = *(const bf16x8*)&xs[wm + 16 * mf + (lane & 15)][kc];
            #pragma unroll
            for (int nf = 0; nf < 4; ++nf)
                bfr[nf] = *(const bf16x8*)&wsm[wn + 16 * nf + (lane & 15)][kc];
            #pragma unroll
            for (int mf = 0; mf < 4; ++mf)
                #pragma unroll
                for (int nf = 0; nf < 4; ++nf)
                    acc[mf][nf] = MFMA16(af[mf], bfr[nf], acc[mf][nf]);
        }
    }

    const int col_l = lane & 15, rgrp = lane >> 4;
    if (blockIdx.z != 2) {
        unsigned short* out = (blockIdx.z == 0) ? Qo : Ko;
        const float oscale = (blockIdx.z == 0) ? SCL : 1.0f;
        #pragma unroll
        for (int nf = 0; nf < 4; ++nf) {
            const int n = n0 + wn + 16 * nf + col_l;
            const float bval = bias[n];
            const int h = n >> 6, d = n & 63;
            #pragma unroll
            for (int mf = 0; mf < 4; ++mf)
                #pragma unroll
                for (int r = 0; r < 4; ++r) {
                    int m = m0 + wm + 16 * mf + 4 * rgrp + r;
                    int bI = m >> 11, s = m & 2047;
                    out[(((size_t)bI * H_ + h) * S_ + s) * HD_ + d]
                        = f2b((acc[mf][nf][r] + bval) * oscale);
                }
        }
    } else {
        #pragma unroll
        for (int nf = 0; nf < 4; ++nf) {
            const int n = n0 + wn + 16 * nf + col_l;
            const float bval = bias[n];
            const int h = n >> 6, d = n & 63;
            #pragma unroll
            for (int mf = 0; mf < 4; ++mf) {
                int m = m0 + wm + 16 * mf + 4 * rgrp;   // 4 consecutive s
                int bI = m >> 11, s = m & 2047;
                ushort4 o;
                o.x = f2b(acc[mf][nf][0] + bval);
                o.y = f2b(acc[mf][nf][1] + bval);
                o.z = f2b(acc[mf][nf][2] + bval);
                o.w = f2b(acc[mf][nf][3] + bval);
                *(ushort4*)&VT[(((size_t)bI * H_ + h) * HD_ + d) * S_ + s] = o;
            }
        }
    }
}

// ---------------------------------------------------------------------------
// K2: attention pass 1 (bf16 MFMA).  Per block: one (b,h), 128 q-rows.
// Swapped QK^T (mfma(K,Q)); V read from VT (pre-transposed) -> conflict-free
// vector staging, no LDS transpose.  XCD-swizzled block mapping: all 16
// q-tiles of one (b,h) land on the same XCD (K/V stay in that XCD's L2).
// l = sum exp2(s'); outputs L and PPOOL (pooled partials).
// ---------------------------------------------------------------------------
__global__ __launch_bounds__(256) void attn_ctx_k(
    const unsigned short* __restrict__ Q, const unsigned short* __restrict__ K,
    const unsigned short* __restrict__ VT,
    float* __restrict__ L, float* __restrict__ PPOOL)
{
    __shared__ unsigned short ks[64][72];
    __shared__ unsigned short vt[64][72];   // vt[d][kpos], staged from VT
    __shared__ unsigned short ps[128][72];  // P, wave-private row stripes
    __shared__ float pp[4][64];             // per-wave pooled partials
    __shared__ float lsm[4][32];            // per-wave l by local q-row

    // XCD swizzle: lin = (g&7) + 8*qb + 128*(g>>3)  (bijective, 1024 blocks)
    const int lin = blockIdx.x;
    const int g   = (lin & 7) | ((lin >> 7) << 3);   // bh index 0..63
    const int qb  = (lin >> 3) & 15;
    const int b   = g >> 4, h = g & 15;
    const int q0  = qb * 128;

    const size_t hoff = ((size_t)(b * H_ + h)) * S_ * HD_;
    const unsigned short* Qh  = Q  + hoff;
    const unsigned short* Kh  = K  + hoff;
    const unsigned short* VTh = VT + hoff;   // [HD][S]

    const int tid = threadIdx.x, lane = tid & 63, wid = tid >> 6;
    const int srow = tid >> 3;       // 0..31
    const int skc  = (tid & 7) * 8;
    const int col_l = lane & 15, rgrp = lane >> 4;

    bf16x8 qf[2][2];
    #pragma unroll
    for (int i = 0; i < 2; ++i)
        #pragma unroll
        for (int kd = 0; kd < 2; ++kd)
            qf[i][kd] = *(const bf16x8*)&Qh[(size_t)(q0 + 32 * wid + 16 * i + col_l) * HD_
                                            + 32 * kd + 8 * rgrp];

    f32x4 cacc[2][4] = {};
    float lp[2] = {};

    for (int kb = 0; kb < S_; kb += 64) {
        u16x8 ka[2], va[2];
        #pragma unroll
        for (int r = 0; r < 2; ++r) {
            int row = srow + 32 * r;
            ka[r] = *(const u16x8*)&Kh [(size_t)(kb + row) * HD_ + skc];
            va[r] = *(const u16x8*)&VTh[(size_t)row * S_ + kb + skc];
        }
        __syncthreads();   // everyone done reading previous ks/vt
        #pragma unroll
        for (int r = 0; r < 2; ++r) {
            int row = srow + 32 * r;
            *(u16x8*)&ks[row][skc] = ka[r];
            *(u16x8*)&vt[row][skc] = va[r];
        }
        __syncthreads();

        // S^T = K Q^T per n-block of 16 k-rows; exp; pack; stage to ps
        #pragma unroll
        for (int n = 0; n < 4; ++n) {
            f32x4 s0 = {}, s1 = {};
            #pragma unroll
            for (int kd = 0; kd < 2; ++kd) {
                const int kc = 32 * kd + 8 * rgrp;
                bf16x8 kf = *(const bf16x8*)&ks[16 * n + col_l][kc];
                s0 = MFMA16(kf, qf[0][kd], s0);
                s1 = MFMA16(kf, qf[1][kd], s1);
            }
            float e0 = exp2f(s0[0]), e1 = exp2f(s0[1]), e2 = exp2f(s0[2]), e3 = exp2f(s0[3]);
            lp[0] += (e0 + e1) + (e2 + e3);
            uint2 w0 = { cvtpk_bf16(e0, e1), cvtpk_bf16(e2, e3) };
            *(uint2*)&ps[32 * wid + col_l][16 * n + 4 * rgrp] = w0;
            float f0 = exp2f(s1[0]), f1 = exp2f(s1[1]), f2 = exp2f(s1[2]), f3 = exp2f(s1[3]);
            lp[1] += (f0 + f1) + (f2 + f3);
            uint2 w1 = { cvtpk_bf16(f0, f1), cvtpk_bf16(f2, f3) };
            *(uint2*)&ps[32 * wid + 16 + col_l][16 * n + 4 * rgrp] = w1;
        }

        // ctx += P @ V  (same-wave LDS RAW; compiler inserts lgkmcnt)
        #pragma unroll
        for (int kk = 0; kk < 2; ++kk) {
            const int kc = 32 * kk + 8 * rgrp;
            bf16x8 pa[2], vf[4];
            #pragma unroll
            for (int i = 0; i < 2; ++i)
                pa[i] = *(const bf16x8*)&ps[32 * wid + 16 * i + col_l][kc];
            #pragma unroll
            for (int n = 0; n < 4; ++n)
                vf[n] = *(const bf16x8*)&vt[16 * n + col_l][kc];
            #pragma unroll
            for (int i = 0; i < 2; ++i)
                #pragma unroll
                for (int n = 0; n < 4; ++n)
                    cacc[i][n] = MFMA16(pa[i], vf[n], cacc[i][n]);
        }
    }

    // reduce l over the 4 rgrp lane groups (each holds a disjoint k-subset)
    #pragma unroll
    for (int i = 0; i < 2; ++i) {
        float v = lp[i];
        v += __shfl_xor(v, 16); v += __shfl_xor(v, 32);
        lp[i] = v;
    }
    if (lane < 16) {
        #pragma unroll
        for (int i = 0; i < 2; ++i) {
            L[((size_t)(b * H_ + h)) * S_ + q0 + 32 * wid + 16 * i + lane] = lp[i];
            lsm[wid][16 * i + lane] = lp[i];
        }
    }

    // pooled partial: sum over this wave's 32 q-rows of cacc/l, per head-dim
    float pool4[4] = {};
    #pragma unroll
    for (int i = 0; i < 2; ++i)
        #pragma unroll
        for (int r = 0; r < 4; ++r) {
            float inv = 1.0f / lsm[wid][16 * i + 4 * rgrp + r];
            #pragma unroll
            for (int n = 0; n < 4; ++n)
                pool4[n] = fmaf(cacc[i][n][r], inv, pool4[n]);
        }
    #pragma unroll
    for (int n = 0; n < 4; ++n) {
        float v = pool4[n];
        v += __shfl_xor(v, 16); v += __shfl_xor(v, 32);
        pool4[n] = v;
    }
    if (lane < 16) {
        #pragma unroll
        for (int n = 0; n < 4; ++n) pp[wid][16 * n + lane] = pool4[n];
    }
    __syncthreads();
    if (tid < 64) {
        float s = pp[0][tid] + pp[1][tid] + pp[2][tid] + pp[3][tid];
        PPOOL[((size_t)(b * H_ + h) * (S_ / 128) + qb) * 64 + tid] = s;
    }
}

// ---------------------------------------------------------------------------
// K3: attn_mean[b,q,k] = (1/16) sum_h exp2(s'_h)/l_h — second score pass.
// LDS-staged Q (128x64) and K (64x64) tiles per head; swapped MFMA so the
// epilogue is dwordx4 stores and l is loaded twice (not 8x) per head.
// ---------------------------------------------------------------------------
__global__ __launch_bounds__(256) void attn_mean_k(
    const unsigned short* __restrict__ Q, const unsigned short* __restrict__ K,
    const float* __restrict__ L, float* __restrict__ attn_out)
{
    __shared__ unsigned short qs[128][72];
    __shared__ unsigned short ksm[64][72];
    __shared__ float lsm[128];

    const int k0 = blockIdx.x * 64, q0 = blockIdx.y * 128, b = blockIdx.z;
    const int tid = threadIdx.x, lane = tid & 63, wid = tid >> 6;
    const int col_l = lane & 15, rgrp = lane >> 4;
    const int qrow = tid >> 1, qcol = (tid & 1) * 32;   // Q staging: 32 elems/thread
    const int krow = tid >> 2, kcol = (tid & 3) * 16;   // K staging: 16 elems/thread

    f32x4 macc[4][2] = {};   // [n: k-16-block][i: q-16-block]

    for (int h = 0; h < H_; ++h) {
        const size_t hoff = ((size_t)(b * H_ + h)) * S_ * HD_;
        const unsigned short* Qh = Q + hoff;
        const unsigned short* Kh = K + hoff;

        u16x8 qa[4], ka[2];
        #pragma unroll
        for (int j = 0; j < 4; ++j)
            qa[j] = *(const u16x8*)&Qh[(size_t)(q0 + qrow) * HD_ + qcol + 8 * j];
        #pragma unroll
        for (int j = 0; j < 2; ++j)
            ka[j] = *(const u16x8*)&Kh[(size_t)(k0 + krow) * HD_ + kcol + 8 * j];
        float lval = 0.f;
        if (tid < 128) lval = L[((size_t)(b * H_ + h)) * S_ + q0 + tid];

        __syncthreads();   // previous head's compute done
        #pragma unroll
        for (int j = 0; j < 4; ++j) *(u16x8*)&qs[qrow][qcol + 8 * j] = qa[j];
        #pragma unroll
        for (int j = 0; j < 2; ++j) *(u16x8*)&ksm[krow][kcol + 8 * j] = ka[j];
        if (tid < 128) lsm[tid] = lval;
        __syncthreads();

        bf16x8 qf[2][2];
        #pragma unroll
        for (int i = 0; i < 2; ++i)
            #pragma unroll
            for (int kd = 0; kd < 2; ++kd)
                qf[i][kd] = *(const bf16x8*)&qs[32 * wid + 16 * i + col_l][32 * kd + 8 * rgrp];

        float li0 = 0.0625f / lsm[32 * wid + col_l];
        float li1 = 0.0625f / lsm[32 * wid + 16 + col_l];

        #pragma unroll
        for (int n = 0; n < 4; ++n) {
            f32x4 s0 = {}, s1 = {};
            #pragma unroll
            for (int kd = 0; kd < 2; ++kd) {
                bf16x8 kf = *(const bf16x8*)&ksm[16 * n + col_l][32 * kd + 8 * rgrp];
                s0 = MFMA16(kf, qf[0][kd], s0);
                s1 = MFMA16(kf, qf[1][kd], s1);
            }
            #pragma unroll
            for (int r = 0; r < 4; ++r) {
                macc[n][0][r] = fmaf(exp2f(s0[r]), li0, macc[n][0][r]);
                macc[n][1][r] = fmaf(exp2f(s1[r]), li1, macc[n][1][r]);
            }
        }
    }

    #pragma unroll
    for (int n = 0; n < 4; ++n)
        #pragma unroll
        for (int i = 0; i < 2; ++i) {
            int q = q0 + 32 * wid + 16 * i + col_l;
            *(f32x4*)&attn_out[((size_t)b * S_ + q) * S_ + k0 + 16 * n + 4 * rgrp]
                = macc[n][i];
        }
}

// ---------------------------------------------------------------------------
// K4: out[b,j] = pooled[b,:] . wo[j,:] + bo[j], pooled reduced from PPOOL.
// ---------------------------------------------------------------------------
__global__ __launch_bounds__(256) void out_k(
    const float* __restrict__ PPOOL, const float* __restrict__ wo,
    const float* __restrict__ bo, float* __restrict__ out)
{
    __shared__ float psm[D_];
    const int b = blockIdx.x >> 2;
    for (int d = threadIdx.x; d < D_; d += 256) {
        const float* pp = PPOOL + ((size_t)(b * H_ + (d >> 6)) * (S_ / 128)) * 64 + (d & 63);
        float s = 0.f;
        #pragma unroll
        for (int qb = 0; qb < S_ / 128; ++qb) s += pp[qb * 64];
        psm[d] = s * (1.0f / S_);
    }
    __syncthreads();
    const int j = (blockIdx.x & 3) * 256 + threadIdx.x;
    float sum = bo[j];
    const float* wr = wo + (size_t)j * D_;
    for (int d = 0; d < D_; d += 4) {
        float4 w4 = *(const float4*)&wr[d];
        sum += psm[d] * w4.x + psm[d+1] * w4.y + psm[d+2] * w4.z + psm[d+3] * w4.w;
    }
    out[b * D_ + j] = sum;
}

// ---------------------------------------------------------------------------
extern "C" void kernel_launch(void* const* d_in, const int* in_sizes, int n_in,
                              void* d_out, int out_size, void* d_ws, size_t ws_size,
                              hipStream_t stream)
{
    const float* x  = (const float*)d_in[0];
    const float* wq = (const float*)d_in[1];
    const float* bq = (const float*)d_in[2];
    const float* wk = (const float*)d_in[3];
    const float* bk = (const float*)d_in[4];
    const float* wv = (const float*)d_in[5];
    const float* bv = (const float*)d_in[6];
    const float* wo = (const float*)d_in[7];
    const float* bo = (const float*)d_in[8];
    float* out = (float*)d_out;

    char* ws = (char*)d_ws;
    const size_t XN  = (size_t)M_ * D_;            // 8,388,608
    const size_t WN  = (size_t)D_ * D_;            // 1,048,576
    const size_t QN  = (size_t)B_ * H_ * S_ * HD_; // 8,388,608

    unsigned short* xb  = (unsigned short*)ws;                 ws += XN * 2;   // 16 MB
    unsigned short* wqb = (unsigned short*)ws;                 ws += WN * 2;   // 2 MB
    unsigned short* wkb = (unsigned short*)ws;                 ws += WN * 2;
    unsigned short* wvb = (unsigned short*)ws;                 ws += WN * 2;
    unsigned short* Qb  = (unsigned short*)ws;                 ws += QN * 2;   // 16 MB
    unsigned short* Kb  = (unsigned short*)ws;                 ws += QN * 2;
    unsigned short* VTb = (unsigned short*)ws;                 ws += QN * 2;   // [B][H][HD][S]
    float* Lb    = (float*)ws;                                 ws += (size_t)B_ * H_ * S_ * 4;
    float* PPOOL = (float*)ws;   // B*H*(S/128)*64 = 65536 floats = 256 KB

    cast_k<<<dim3(XN / 1024), 256, 0, stream>>>(x, xb, (int)XN);
    cast3_k<<<dim3(WN / 1024, 3), 256, 0, stream>>>(wq, wk, wv, wqb, wkb, wvb, (int)WN);

    qkv_gemm_k<<<dim3(M_ / 128, D_ / 128, 3), 256, 0, stream>>>(
        xb, wqb, wkb, wvb, bq, bk, bv, Qb, Kb, VTb);
    attn_ctx_k<<<dim3(1024), 256, 0, stream>>>(Qb, Kb, VTb, Lb, PPOOL);
    attn_mean_k<<<dim3(S_ / 64, S_ / 128, B_), 256, 0, stream>>>(Qb, Kb, Lb, out + B_ * D_);
    out_k<<<16, 256, 0, stream>>>(PPOOL, wo, bo, out);
}